// Round 13
// baseline (311.085 us; speedup 1.0000x reference)
//
#include <hip/hip_runtime.h>
#include <hip/hip_fp16.h>

#define N_NODES 50000
#define E_EDGES 800000
#define ETOT (E_EDGES + N_NODES)   // self-loops appended
#define IN_CH 128
#define HH 128                     // HEADS*HID
#define HEADS 4
#define HID 32
#define OUT_CH 32
#define NEG 0.2f

#define GEMM_BLOCKS ((N_NODES + 127) / 128)   // 391
#define NB_HIST 16
#define EPB (ETOT / NB_HIST)                  // 53125 exactly (850000 = 16*53125)
#define QN 12544                              // nodes per LDS-hist quarter (4*QN >= N)
#define CNT_STRIDE 50176
#define XP 132                                // padded LDS row stride (floats)

// ===== fused: [0..390] xw1 = x@W1 + att dots ; [391..406] LDS-hist edge-rank =====
__global__ __launch_bounds__(256, 2) void gemm1_fused(const float* __restrict__ x,
                                                      const float* __restrict__ W1,
                                                      const float* __restrict__ att_s,
                                                      const float* __restrict__ att_d,
                                                      const int* __restrict__ ei,
                                                      __half* __restrict__ xwh,
                                                      float* __restrict__ a1s,
                                                      float* __restrict__ a1d,
                                                      int* __restrict__ idx,
                                                      int* __restrict__ cnt) {
    __shared__ __align__(16) char smem[QN * 4];   // 50176 B: hist(50K) | GEMM tiles(33.8K)
    int t = threadIdx.x;

    if (blockIdx.x >= GEMM_BLOCKS) {
        // ---------- LDS-histogram edge-rank: idx[e] = rank within (block, dst) ----------
        int b = blockIdx.x - GEMM_BLOCKS;          // 0..15
        int* hist = (int*)smem;                    // QN ints
        const int e0 = b * EPB, e1 = e0 + EPB;
        for (int q = 0; q < 4; ++q) {
            int dlo = q * QN;
            int dcnt = (N_NODES - dlo < QN) ? (N_NODES - dlo) : QN;
            for (int i = t; i < QN; i += 256) hist[i] = 0;
            __syncthreads();
            for (int i0 = e0 + t; i0 < e1; i0 += 1024) {
#pragma unroll
                for (int k = 0; k < 4; ++k) {
                    int e = i0 + k * 256;
                    if (e < e1) {
                        int d = (e < E_EDGES) ? ei[E_EDGES + e] : e - E_EDGES;
                        int r = d - dlo;
                        if ((unsigned)r < (unsigned)dcnt)
                            idx[e] = atomicAdd(&hist[r], 1);
                    }
                }
            }
            __syncthreads();
            for (int i = t; i < dcnt; i += 256) cnt[b * CNT_STRIDE + dlo + i] = hist[i];
            __syncthreads();
        }
        return;
    }

    // ---------- GEMM part: 128x128 tile, BK=32, 8x8 micro-tile (flat smem) ----------
    float* Xs = (float*)smem;                      // [32][XP]
    float* Ws = (float*)(smem + 32 * XP * 4);      // [32][XP]  (2*16896B = 33792 <= 50176)
    int tx = t & 15, ty = t >> 4;
    int row0 = blockIdx.x * 128;
    float acc[8][8] = {};

    for (int k0 = 0; k0 < IN_CH; k0 += 32) {
#pragma unroll
        for (int p = 0; p < 4; ++p) {
            int i2 = t + p * 256;
            int kk = i2 >> 5, c4 = i2 & 31;
            float4 v = *(const float4*)&W1[(size_t)(k0 + kk) * HH + c4 * 4];
            *(float4*)&Ws[kk * XP + c4 * 4] = v;
        }
#pragma unroll
        for (int p = 0; p < 4; ++p) {
            int i2 = t + p * 256;
            int rr = i2 >> 3, c4 = i2 & 7;
            int row = row0 + rr;
            float4 v = make_float4(0.f, 0.f, 0.f, 0.f);
            if (row < N_NODES) v = *(const float4*)&x[(size_t)row * IN_CH + k0 + c4 * 4];
            Xs[(c4 * 4 + 0) * XP + rr] = v.x;
            Xs[(c4 * 4 + 1) * XP + rr] = v.y;
            Xs[(c4 * 4 + 2) * XP + rr] = v.z;
            Xs[(c4 * 4 + 3) * XP + rr] = v.w;
        }
        __syncthreads();
#pragma unroll 8
        for (int kk = 0; kk < 32; ++kk) {
            float4 xa0 = *(const float4*)&Xs[kk * XP + ty * 4];
            float4 xa1 = *(const float4*)&Xs[kk * XP + ty * 4 + 64];
            float4 wb0 = *(const float4*)&Ws[kk * XP + tx * 4];
            float4 wb1 = *(const float4*)&Ws[kk * XP + tx * 4 + 64];
            float xa[8] = {xa0.x, xa0.y, xa0.z, xa0.w, xa1.x, xa1.y, xa1.z, xa1.w};
            float wb[8] = {wb0.x, wb0.y, wb0.z, wb0.w, wb1.x, wb1.y, wb1.z, wb1.w};
#pragma unroll
            for (int i = 0; i < 8; ++i)
#pragma unroll
                for (int j = 0; j < 8; ++j)
                    acc[i][j] = fmaf(xa[i], wb[j], acc[i][j]);
        }
        __syncthreads();
    }

    float asr[8], adr[8];
#pragma unroll
    for (int j = 0; j < 8; ++j) {
        int col = tx * 4 + (j & 3) + ((j >> 2) << 6);
        asr[j] = att_s[col];
        adr[j] = att_d[col];
    }
    int hA = tx >> 3;

#pragma unroll
    for (int i = 0; i < 8; ++i) {
        int row = row0 + ty * 4 + (i < 4 ? i : 60 + i);
        if (row < N_NODES) {
            union { __half2 h2; unsigned u; } c0, c1, c2, c3;
            c0.h2 = __floats2half2_rn(acc[i][0], acc[i][1]);
            c1.h2 = __floats2half2_rn(acc[i][2], acc[i][3]);
            c2.h2 = __floats2half2_rn(acc[i][4], acc[i][5]);
            c3.h2 = __floats2half2_rn(acc[i][6], acc[i][7]);
            *(uint2*)&xwh[(size_t)row * HH + tx * 4]      = make_uint2(c0.u, c1.u);
            *(uint2*)&xwh[(size_t)row * HH + tx * 4 + 64] = make_uint2(c2.u, c3.u);
        }
        float psA = 0.f, pdA = 0.f, psB = 0.f, pdB = 0.f;
#pragma unroll
        for (int j = 0; j < 4; ++j) {
            psA = fmaf(acc[i][j], asr[j], psA);
            pdA = fmaf(acc[i][j], adr[j], pdA);
            psB = fmaf(acc[i][j + 4], asr[j + 4], psB);
            pdB = fmaf(acc[i][j + 4], adr[j + 4], pdB);
        }
#pragma unroll
        for (int off = 1; off < 8; off <<= 1) {
            psA += __shfl_xor(psA, off, 16);
            pdA += __shfl_xor(pdA, off, 16);
            psB += __shfl_xor(psB, off, 16);
            pdB += __shfl_xor(pdB, off, 16);
        }
        if ((tx & 7) == 0 && row < N_NODES) {
            a1s[row * 4 + hA]     = psA;
            a1d[row * 4 + hA]     = pdA;
            a1s[row * 4 + hA + 2] = psB;
            a1d[row * 4 + hA + 2] = pdB;
        }
    }
}

// ===== col_scan: per-node exclusive prefix over the 16 block counts (in place) =====
__global__ void col_scan(int* __restrict__ cnt, int* __restrict__ deg) {
    int d = blockIdx.x * 256 + threadIdx.x;
    if (d >= N_NODES) return;
    int s = 0;
#pragma unroll
    for (int b = 0; b < NB_HIST; ++b) {
        int c = cnt[b * CNT_STRIDE + d];
        cnt[b * CNT_STRIDE + d] = s;
        s += c;
    }
    deg[d] = s;
}

// ================= scan (rowptr from deg) =================
__device__ __forceinline__ int block_incl_scan(int v, int t) {
    for (int off = 1; off < 64; off <<= 1) {
        int n = __shfl_up(v, off, 64);
        if ((t & 63) >= off) v += n;
    }
    __shared__ int wsum[4];
    if ((t & 63) == 63) wsum[t >> 6] = v;
    __syncthreads();
    int w = t >> 6;
    if (w > 0) {
        int add = 0;
        for (int k = 0; k < w; ++k) add += wsum[k];
        v += add;
    }
    __syncthreads();
    return v;
}

#define NCHUNK ((N_NODES + 255) / 256)   // 196

__global__ void scan_s1(const int* __restrict__ deg, int* __restrict__ rowptr,
                        int* __restrict__ partials) {
    int t = threadIdx.x;
    int i = blockIdx.x * 256 + t;
    int v = (i < N_NODES) ? deg[i] : 0;
    int s = block_incl_scan(v, t);
    if (i < N_NODES) rowptr[i + 1] = s;
    if (t == 255) partials[blockIdx.x] = s;
}

__global__ void scan_s2(int* __restrict__ partials) {
    int t = threadIdx.x;
    int v = (t < NCHUNK) ? partials[t] : 0;
    int s = block_incl_scan(v, t);
    if (t < NCHUNK) partials[t] = s;
}

__global__ void scan_s3(int* __restrict__ rowptr, const int* __restrict__ partials) {
    int i = blockIdx.x * blockDim.x + threadIdx.x;
    if (i == 0) rowptr[0] = 0;
    if (i < N_NODES) {
        int c = i >> 8;
        if (c > 0) rowptr[i + 1] += partials[c - 1];
    }
}

// ====== place: csr_src[rowptr[d] + blockbase[b][d] + idx[e]] = s (no atomics) ======
__global__ void place_csr(const int* __restrict__ ei, const int* __restrict__ idx,
                          const int* __restrict__ rowptr, const int* __restrict__ cnt,
                          int* __restrict__ csr_src) {
    int e = blockIdx.x * blockDim.x + threadIdx.x;
    if (e >= ETOT) return;
    int s, d;
    if (e < E_EDGES) { s = ei[e]; d = ei[E_EDGES + e]; }
    else { s = e - E_EDGES; d = s; }
    int b = e / EPB;
    csr_src[rowptr[d] + cnt[b * CNT_STRIDE + d] + idx[e]] = s;
}

// ========== layer-1 gather + fused denom + FUSED gemm2/att-dots ==========
// 2 nodes per 64-lane wave: 32 lanes/node, 4 channels/lane (8B gather per lane).
__global__ void gather1_g2(const int* __restrict__ rowptr, const int* __restrict__ csr_src,
                           const float* __restrict__ a1s, const float* __restrict__ a1d,
                           const __half* __restrict__ xwh,
                           const float* __restrict__ b1, const float* __restrict__ W2,
                           const float* __restrict__ att_s2, const float* __restrict__ att_d2,
                           __half* __restrict__ hw2h,
                           float* __restrict__ a2s, float* __restrict__ a2d) {
    __shared__ float Wl[HH * OUT_CH];   // W2 [j*32+o], 16 KiB; lane o -> bank o
    __shared__ float hs[8][HH];         // per-node h rows, 4 KiB
    int t = threadIdx.x;
    for (int i = t; i < HH * OUT_CH; i += 256) Wl[i] = W2[i];
    __syncthreads();

    int wid = t >> 5;                    // node slot 0..7
    int d = blockIdx.x * 8 + wid;
    int l = t & 31;                      // channels 4l..4l+3; head = l>>3
    int h = l >> 3;
    float ad = a1d[d * 4 + h];
    int p0 = rowptr[d], p1 = rowptr[d + 1];
    float acc0 = 0.f, acc1 = 0.f, acc2 = 0.f, acc3 = 0.f, wsum = 0.f;
    union { float2 f2; __half2 h2[2]; } u0, u1, u2, u3;
    int p = p0;
    for (; p + 3 < p1; p += 4) {
        int s0 = csr_src[p], s1 = csr_src[p + 1], s2 = csr_src[p + 2], s3 = csr_src[p + 3];
        float v0 = a1s[s0 * 4 + h] + ad; v0 = v0 > 0.f ? v0 : NEG * v0;
        float v1 = a1s[s1 * 4 + h] + ad; v1 = v1 > 0.f ? v1 : NEG * v1;
        float v2 = a1s[s2 * 4 + h] + ad; v2 = v2 > 0.f ? v2 : NEG * v2;
        float v3 = a1s[s3 * 4 + h] + ad; v3 = v3 > 0.f ? v3 : NEG * v3;
        float w0 = __expf(v0), w1 = __expf(v1), w2 = __expf(v2), w3 = __expf(v3);
        u0.f2 = *(const float2*)&xwh[(size_t)s0 * HH + 4 * l];
        u1.f2 = *(const float2*)&xwh[(size_t)s1 * HH + 4 * l];
        u2.f2 = *(const float2*)&xwh[(size_t)s2 * HH + 4 * l];
        u3.f2 = *(const float2*)&xwh[(size_t)s3 * HH + 4 * l];
#define FM(k, W) { float2 fa = __half22float2(u##k.h2[0]); float2 fb = __half22float2(u##k.h2[1]); \
                   acc0 = fmaf(W, fa.x, acc0); acc1 = fmaf(W, fa.y, acc1); \
                   acc2 = fmaf(W, fb.x, acc2); acc3 = fmaf(W, fb.y, acc3); }
        FM(0, w0) FM(1, w1) FM(2, w2) FM(3, w3)
#undef FM
        wsum += (w0 + w1) + (w2 + w3);
    }
    for (; p < p1; ++p) {
        int s = csr_src[p];
        float v = a1s[s * 4 + h] + ad; v = v > 0.f ? v : NEG * v;
        float w = __expf(v);
        u0.f2 = *(const float2*)&xwh[(size_t)s * HH + 4 * l];
        float2 fa = __half22float2(u0.h2[0]);
        float2 fb = __half22float2(u0.h2[1]);
        acc0 = fmaf(w, fa.x, acc0); acc1 = fmaf(w, fa.y, acc1);
        acc2 = fmaf(w, fb.x, acc2); acc3 = fmaf(w, fb.y, acc3);
        wsum += w;
    }
    float r = 1.f / (wsum + 1e-16f);
    float4 bv = *(const float4*)&b1[4 * l];
    float h0 = acc0 * r + bv.x;
    float h1 = acc1 * r + bv.y;
    float h2v = acc2 * r + bv.z;
    float h3v = acc3 * r + bv.w;
    h0  = h0  > 0.f ? h0  : (__expf(h0)  - 1.f);   // ELU
    h1  = h1  > 0.f ? h1  : (__expf(h1)  - 1.f);
    h2v = h2v > 0.f ? h2v : (__expf(h2v) - 1.f);
    h3v = h3v > 0.f ? h3v : (__expf(h3v) - 1.f);
    *(float4*)&hs[wid][4 * l] = make_float4(h0, h1, h2v, h3v);
    // same-wave LDS write->read: compiler enforces lgkmcnt ordering (wave-private rows)

    // ---- gemm2 part: out[o] = sum_j h[j]*W2[j][o]; lane o = l, full 128-dot ----
    const float* hrow = hs[wid];
    const float* wcol = &Wl[l];
    float acc = 0.f;
#pragma unroll 8
    for (int j = 0; j < 128; ++j) acc = fmaf(hrow[j], wcol[j * OUT_CH], acc);

    hw2h[(size_t)d * OUT_CH + l] = __float2half_rn(acc);

    float ps = acc * att_s2[l], pd = acc * att_d2[l];
#pragma unroll
    for (int off = 16; off; off >>= 1) {
        ps += __shfl_xor(ps, off, 32);
        pd += __shfl_xor(pd, off, 32);
    }
    if (l == 0) { a2s[d] = ps; a2d[d] = pd; }
}

// ========== layer-2 gather-aggregate, fused denominator, 4-edge ILP ==========
__global__ void gather2(const int* __restrict__ rowptr, const int* __restrict__ csr_src,
                        const float* __restrict__ a2s, const float* __restrict__ a2d,
                        const __half* __restrict__ hw2h, const float* __restrict__ b2,
                        float* __restrict__ out) {
    int t = threadIdx.x;
    int d = blockIdx.x * 8 + (t >> 5);   // 32 lanes per node
    if (d >= N_NODES) return;
    int o = t & 31;
    float ad = a2d[d];
    int p0 = rowptr[d], p1 = rowptr[d + 1];
    float acc = 0.f, wsum = 0.f;
    int p = p0;
    for (; p + 3 < p1; p += 4) {
        int s0 = csr_src[p], s1 = csr_src[p + 1], s2 = csr_src[p + 2], s3 = csr_src[p + 3];
        float v0 = a2s[s0] + ad; v0 = v0 > 0.f ? v0 : NEG * v0;
        float v1 = a2s[s1] + ad; v1 = v1 > 0.f ? v1 : NEG * v1;
        float v2 = a2s[s2] + ad; v2 = v2 > 0.f ? v2 : NEG * v2;
        float v3 = a2s[s3] + ad; v3 = v3 > 0.f ? v3 : NEG * v3;
        float w0 = __expf(v0), w1 = __expf(v1), w2 = __expf(v2), w3 = __expf(v3);
        float x0 = __half2float(hw2h[(size_t)s0 * OUT_CH + o]);
        float x1 = __half2float(hw2h[(size_t)s1 * OUT_CH + o]);
        float x2 = __half2float(hw2h[(size_t)s2 * OUT_CH + o]);
        float x3 = __half2float(hw2h[(size_t)s3 * OUT_CH + o]);
        acc = fmaf(w0, x0, acc); acc = fmaf(w1, x1, acc);
        acc = fmaf(w2, x2, acc); acc = fmaf(w3, x3, acc);
        wsum += (w0 + w1) + (w2 + w3);
    }
    for (; p < p1; ++p) {
        int s = csr_src[p];
        float v = a2s[s] + ad; v = v > 0.f ? v : NEG * v;
        float w = __expf(v);
        acc = fmaf(w, __half2float(hw2h[(size_t)s * OUT_CH + o]), acc);
        wsum += w;
    }
    out[(size_t)d * OUT_CH + o] = acc / (wsum + 1e-16f) + b2[o];
}

extern "C" void kernel_launch(void* const* d_in, const int* in_sizes, int n_in,
                              void* d_out, int out_size, void* d_ws, size_t ws_size,
                              hipStream_t stream) {
    const float* x   = (const float*)d_in[0];
    const int*   ei  = (const int*)d_in[1];     // int32 (JAX x64 off)
    const float* W1  = (const float*)d_in[2];
    const float* as1 = (const float*)d_in[3];
    const float* ad1 = (const float*)d_in[4];
    const float* b1  = (const float*)d_in[5];
    const float* W2  = (const float*)d_in[6];
    const float* as2 = (const float*)d_in[7];
    const float* ad2 = (const float*)d_in[8];
    const float* b2  = (const float*)d_in[9];
    float* out = (float*)d_out;
    float* ws  = (float*)d_ws;

    // workspace layout (float offsets); peak 7,103,088 floats = 28.4 MB
    __half* xwh   = (__half*)ws;               // 6.4M halves (3.2M floats)
    __half* hw2h  = (__half*)(ws + 3200000);   // 1.6M halves (800K floats)
    float* a1s    = ws + 4000000;              // 200,000
    float* a1d    = ws + 4200000;              // 200,000
    float* a2s    = ws + 4400000;              //  50,000
    float* a2d    = ws + 4450000;              //  50,000
    int*   deg    = (int*)(ws + 4500000);      //  50,000
    int*   rowptr = (int*)(ws + 4550000);      //  50,016
    int*   parts  = (int*)(ws + 4600016);      //     256
    int*   csr_src= (int*)(ws + 4600272);      // 850,000
    int*   idx    = (int*)(ws + 5450272);      // 850,000
    int*   cnt    = (int*)(ws + 6300272);      // 16*50,176 = 802,816 -> end 7,103,088

    // fused: gemm1 (+att dots) on blocks [0,391), LDS-hist edge-rank on [391,407)
    gemm1_fused<<<GEMM_BLOCKS + NB_HIST, 256, 0, stream>>>(
        x, W1, as1, ad1, ei, xwh, a1s, a1d, idx, cnt);

    col_scan <<<(N_NODES + 255) / 256, 256, 0, stream>>>(cnt, deg);
    scan_s1  <<<NCHUNK, 256, 0, stream>>>(deg, rowptr, parts);
    scan_s2  <<<1, 256, 0, stream>>>(parts);
    scan_s3  <<<(N_NODES + 255) / 256, 256, 0, stream>>>(rowptr, parts);
    place_csr<<<(ETOT + 255) / 256, 256, 0, stream>>>(ei, idx, rowptr, cnt, csr_src);

    gather1_g2<<<N_NODES / 8, 256, 0, stream>>>(rowptr, csr_src, a1s, a1d, xwh,
                                                b1, W2, as2, ad2, hw2h, a2s, a2d);

    gather2  <<<(N_NODES + 7) / 8, 256, 0, stream>>>(rowptr, csr_src, a2s, a2d, hw2h, b2, out);
}

// Round 14
// 161.141 us; speedup vs baseline: 1.9305x; 1.9305x over previous
//
#include <hip/hip_runtime.h>
#include <hip/hip_fp16.h>

#define N_NODES 50000
#define E_EDGES 800000
#define ETOT (E_EDGES + N_NODES)   // self-loops appended
#define IN_CH 128
#define HH 128                     // HEADS*HID
#define HEADS 4
#define HID 32
#define OUT_CH 32
#define NEG 0.2f

#define GEMM_BLOCKS ((N_NODES + 127) / 128)   // 391
#define FILL_BLOCKS ((ETOT + 1023) / 1024)    // 831
#define XP 132                                // padded LDS row stride

// ===== fused: [blocks 0..390] xw1 = x@W1 + att dots ; [391..] edge-rank atomic pass =====
__global__ __launch_bounds__(256, 2) void gemm1_fused(const float* __restrict__ x,
                                                      const float* __restrict__ W1,
                                                      const float* __restrict__ att_s,
                                                      const float* __restrict__ att_d,
                                                      const int* __restrict__ ei,
                                                      __half* __restrict__ xwh,
                                                      float* __restrict__ a1s,
                                                      float* __restrict__ a1d,
                                                      int* __restrict__ deg,
                                                      int* __restrict__ idx) {
    __shared__ float Xs[32][XP];
    __shared__ float Ws[32][XP];
    int t = threadIdx.x;

    if (blockIdx.x >= GEMM_BLOCKS) {
        // ---------- edge-rank pass: idx[e] = rank of e within its dst group ----------
        int base = (blockIdx.x - GEMM_BLOCKS) * 1024 + t;
#pragma unroll
        for (int q = 0; q < 4; ++q) {
            int e = base + q * 256;
            if (e < ETOT) {
                int d = (e < E_EDGES) ? ei[E_EDGES + e] : e - E_EDGES;
                idx[e] = atomicAdd(deg + d, 1);
            }
        }
        return;
    }

    // ---------- GEMM part: 128x128 tile, BK=32, 8x8 micro-tile ----------
    int tx = t & 15, ty = t >> 4;
    int row0 = blockIdx.x * 128;
    float acc[8][8] = {};

    for (int k0 = 0; k0 < IN_CH; k0 += 32) {
#pragma unroll
        for (int p = 0; p < 4; ++p) {
            int i2 = t + p * 256;
            int kk = i2 >> 5, c4 = i2 & 31;
            float4 v = *(const float4*)&W1[(size_t)(k0 + kk) * HH + c4 * 4];
            *(float4*)&Ws[kk][c4 * 4] = v;
        }
#pragma unroll
        for (int p = 0; p < 4; ++p) {
            int i2 = t + p * 256;
            int rr = i2 >> 3, c4 = i2 & 7;
            int row = row0 + rr;
            float4 v = make_float4(0.f, 0.f, 0.f, 0.f);
            if (row < N_NODES) v = *(const float4*)&x[(size_t)row * IN_CH + k0 + c4 * 4];
            Xs[c4 * 4 + 0][rr] = v.x;
            Xs[c4 * 4 + 1][rr] = v.y;
            Xs[c4 * 4 + 2][rr] = v.z;
            Xs[c4 * 4 + 3][rr] = v.w;
        }
        __syncthreads();
#pragma unroll 8
        for (int kk = 0; kk < 32; ++kk) {
            float4 xa0 = *(const float4*)&Xs[kk][ty * 4];
            float4 xa1 = *(const float4*)&Xs[kk][ty * 4 + 64];
            float4 wb0 = *(const float4*)&Ws[kk][tx * 4];
            float4 wb1 = *(const float4*)&Ws[kk][tx * 4 + 64];
            float xa[8] = {xa0.x, xa0.y, xa0.z, xa0.w, xa1.x, xa1.y, xa1.z, xa1.w};
            float wb[8] = {wb0.x, wb0.y, wb0.z, wb0.w, wb1.x, wb1.y, wb1.z, wb1.w};
#pragma unroll
            for (int i = 0; i < 8; ++i)
#pragma unroll
                for (int j = 0; j < 8; ++j)
                    acc[i][j] = fmaf(xa[i], wb[j], acc[i][j]);
        }
        __syncthreads();
    }

    float asr[8], adr[8];
#pragma unroll
    for (int j = 0; j < 8; ++j) {
        int col = tx * 4 + (j & 3) + ((j >> 2) << 6);
        asr[j] = att_s[col];
        adr[j] = att_d[col];
    }
    int hA = tx >> 3;

#pragma unroll
    for (int i = 0; i < 8; ++i) {
        int row = row0 + ty * 4 + (i < 4 ? i : 60 + i);
        if (row < N_NODES) {
            union { __half2 h2; unsigned u; } c0, c1, c2, c3;
            c0.h2 = __floats2half2_rn(acc[i][0], acc[i][1]);
            c1.h2 = __floats2half2_rn(acc[i][2], acc[i][3]);
            c2.h2 = __floats2half2_rn(acc[i][4], acc[i][5]);
            c3.h2 = __floats2half2_rn(acc[i][6], acc[i][7]);
            *(uint2*)&xwh[(size_t)row * HH + tx * 4]      = make_uint2(c0.u, c1.u);
            *(uint2*)&xwh[(size_t)row * HH + tx * 4 + 64] = make_uint2(c2.u, c3.u);
        }
        float psA = 0.f, pdA = 0.f, psB = 0.f, pdB = 0.f;
#pragma unroll
        for (int j = 0; j < 4; ++j) {
            psA = fmaf(acc[i][j], asr[j], psA);
            pdA = fmaf(acc[i][j], adr[j], pdA);
            psB = fmaf(acc[i][j + 4], asr[j + 4], psB);
            pdB = fmaf(acc[i][j + 4], adr[j + 4], pdB);
        }
#pragma unroll
        for (int off = 1; off < 8; off <<= 1) {
            psA += __shfl_xor(psA, off, 16);
            pdA += __shfl_xor(pdA, off, 16);
            psB += __shfl_xor(psB, off, 16);
            pdB += __shfl_xor(pdB, off, 16);
        }
        if ((tx & 7) == 0 && row < N_NODES) {
            a1s[row * 4 + hA]     = psA;
            a1d[row * 4 + hA]     = pdA;
            a1s[row * 4 + hA + 2] = psB;
            a1d[row * 4 + hA + 2] = pdB;
        }
    }
}

// ================= scan (rowptr from deg) =================
__device__ __forceinline__ int block_incl_scan(int v, int t) {
    for (int off = 1; off < 64; off <<= 1) {
        int n = __shfl_up(v, off, 64);
        if ((t & 63) >= off) v += n;
    }
    __shared__ int wsum[4];
    if ((t & 63) == 63) wsum[t >> 6] = v;
    __syncthreads();
    int w = t >> 6;
    if (w > 0) {
        int add = 0;
        for (int k = 0; k < w; ++k) add += wsum[k];
        v += add;
    }
    __syncthreads();
    return v;
}

#define NCHUNK ((N_NODES + 255) / 256)   // 196

__global__ void scan_s1(const int* __restrict__ deg, int* __restrict__ rowptr,
                        int* __restrict__ partials) {
    int t = threadIdx.x;
    int i = blockIdx.x * 256 + t;
    int v = (i < N_NODES) ? deg[i] : 0;
    int s = block_incl_scan(v, t);
    if (i < N_NODES) rowptr[i + 1] = s;
    if (t == 255) partials[blockIdx.x] = s;
}

__global__ void scan_s2(int* __restrict__ partials) {
    int t = threadIdx.x;
    int v = (t < NCHUNK) ? partials[t] : 0;
    int s = block_incl_scan(v, t);
    if (t < NCHUNK) partials[t] = s;
}

__global__ void scan_s3(int* __restrict__ rowptr, const int* __restrict__ partials) {
    int i = blockIdx.x * blockDim.x + threadIdx.x;
    if (i == 0) rowptr[0] = 0;
    if (i < N_NODES) {
        int c = i >> 8;
        if (c > 0) rowptr[i + 1] += partials[c - 1];
    }
}

// ================= place: csr_src[rowptr[d]+idx[e]] = s (no atomics) =================
__global__ void place_csr(const int* __restrict__ ei, const int* __restrict__ idx,
                          const int* __restrict__ rowptr, int* __restrict__ csr_src) {
    int e = blockIdx.x * blockDim.x + threadIdx.x;
    if (e >= ETOT) return;
    int s, d;
    if (e < E_EDGES) { s = ei[e]; d = ei[E_EDGES + e]; }
    else { s = e - E_EDGES; d = s; }
    csr_src[rowptr[d] + idx[e]] = s;
}

// ========== layer-1 gather + fused denom + FUSED gemm2/att-dots ==========
// 2 nodes per 64-lane wave: 32 lanes/node, 4 channels/lane; 8-edge ILP
// -> 16 outstanding 256B gathers per wave. N_NODES % 8 == 0 (no barrier hazard).
__global__ void gather1_g2(const int* __restrict__ rowptr, const int* __restrict__ csr_src,
                           const float* __restrict__ a1s, const float* __restrict__ a1d,
                           const __half* __restrict__ xwh,
                           const float* __restrict__ b1, const float* __restrict__ W2,
                           const float* __restrict__ att_s2, const float* __restrict__ att_d2,
                           __half* __restrict__ hw2h,
                           float* __restrict__ a2s, float* __restrict__ a2d) {
    __shared__ float Wl[HH * OUT_CH];   // W2 [j*32+o], 16 KiB; lane o -> bank o
    __shared__ float hs[8][HH];         // per-node h rows, 4 KiB
    int t = threadIdx.x;
    for (int i = t; i < HH * OUT_CH; i += 256) Wl[i] = W2[i];
    __syncthreads();

    int wid = t >> 5;                    // node slot 0..7
    int d = blockIdx.x * 8 + wid;
    int l = t & 31;                      // channels 4l..4l+3; head = l>>3
    int h = l >> 3;
    float ad = a1d[d * 4 + h];
    int p0 = rowptr[d], p1 = rowptr[d + 1];
    float acc0 = 0.f, acc1 = 0.f, acc2 = 0.f, acc3 = 0.f, wsum = 0.f;
    union HU { float2 f2; __half2 h2[2]; };
    int p = p0;
    for (; p + 7 < p1; p += 8) {
#define LDE(k) int s##k = csr_src[p + k]; \
               float v##k = a1s[s##k * 4 + h] + ad; v##k = v##k > 0.f ? v##k : NEG * v##k; \
               float w##k = __expf(v##k); \
               HU u##k; u##k.f2 = *(const float2*)&xwh[(size_t)s##k * HH + 4 * l];
        LDE(0) LDE(1) LDE(2) LDE(3) LDE(4) LDE(5) LDE(6) LDE(7)
#undef LDE
#define FM(k) { float2 fa = __half22float2(u##k.h2[0]); float2 fb = __half22float2(u##k.h2[1]); \
                acc0 = fmaf(w##k, fa.x, acc0); acc1 = fmaf(w##k, fa.y, acc1); \
                acc2 = fmaf(w##k, fb.x, acc2); acc3 = fmaf(w##k, fb.y, acc3); wsum += w##k; }
        FM(0) FM(1) FM(2) FM(3) FM(4) FM(5) FM(6) FM(7)
#undef FM
    }
    for (; p < p1; ++p) {
        int s = csr_src[p];
        float v = a1s[s * 4 + h] + ad; v = v > 0.f ? v : NEG * v;
        float w = __expf(v);
        HU u0; u0.f2 = *(const float2*)&xwh[(size_t)s * HH + 4 * l];
        float2 fa = __half22float2(u0.h2[0]);
        float2 fb = __half22float2(u0.h2[1]);
        acc0 = fmaf(w, fa.x, acc0); acc1 = fmaf(w, fa.y, acc1);
        acc2 = fmaf(w, fb.x, acc2); acc3 = fmaf(w, fb.y, acc3);
        wsum += w;
    }
    float r = 1.f / (wsum + 1e-16f);
    float4 bv = *(const float4*)&b1[4 * l];
    float h0 = acc0 * r + bv.x;
    float h1 = acc1 * r + bv.y;
    float h2v = acc2 * r + bv.z;
    float h3v = acc3 * r + bv.w;
    h0  = h0  > 0.f ? h0  : (__expf(h0)  - 1.f);   // ELU
    h1  = h1  > 0.f ? h1  : (__expf(h1)  - 1.f);
    h2v = h2v > 0.f ? h2v : (__expf(h2v) - 1.f);
    h3v = h3v > 0.f ? h3v : (__expf(h3v) - 1.f);
    *(float4*)&hs[wid][4 * l] = make_float4(h0, h1, h2v, h3v);
    // same-wave LDS write->read: compiler enforces lgkmcnt ordering (wave-private rows)

    // ---- gemm2 part: out[o] = sum_j h[j]*W2[j][o]; lane o = l, full 128-dot ----
    const float* hrow = hs[wid];
    const float* wcol = &Wl[l];
    float acc = 0.f;
#pragma unroll 8
    for (int j = 0; j < 128; ++j) acc = fmaf(hrow[j], wcol[j * OUT_CH], acc);

    hw2h[(size_t)d * OUT_CH + l] = __float2half_rn(acc);

    float ps = acc * att_s2[l], pd = acc * att_d2[l];
#pragma unroll
    for (int off = 16; off; off >>= 1) {
        ps += __shfl_xor(ps, off, 32);
        pd += __shfl_xor(pd, off, 32);
    }
    if (l == 0) { a2s[d] = ps; a2d[d] = pd; }
}

// ========== layer-2 gather-aggregate, fused denominator, 8-edge ILP ==========
__global__ void gather2(const int* __restrict__ rowptr, const int* __restrict__ csr_src,
                        const float* __restrict__ a2s, const float* __restrict__ a2d,
                        const __half* __restrict__ hw2h, const float* __restrict__ b2,
                        float* __restrict__ out) {
    int t = threadIdx.x;
    int d = blockIdx.x * 8 + (t >> 5);   // 32 lanes per node
    if (d >= N_NODES) return;
    int o = t & 31;
    float ad = a2d[d];
    int p0 = rowptr[d], p1 = rowptr[d + 1];
    float acc = 0.f, wsum = 0.f;
    int p = p0;
    for (; p + 7 < p1; p += 8) {
#define LDE(k) int s##k = csr_src[p + k]; \
               float v##k = a2s[s##k] + ad; v##k = v##k > 0.f ? v##k : NEG * v##k; \
               float w##k = __expf(v##k); \
               float x##k = __half2float(hw2h[(size_t)s##k * OUT_CH + o]);
        LDE(0) LDE(1) LDE(2) LDE(3) LDE(4) LDE(5) LDE(6) LDE(7)
#undef LDE
        acc = fmaf(w0, x0, acc); acc = fmaf(w1, x1, acc);
        acc = fmaf(w2, x2, acc); acc = fmaf(w3, x3, acc);
        acc = fmaf(w4, x4, acc); acc = fmaf(w5, x5, acc);
        acc = fmaf(w6, x6, acc); acc = fmaf(w7, x7, acc);
        wsum += ((w0 + w1) + (w2 + w3)) + ((w4 + w5) + (w6 + w7));
    }
    for (; p < p1; ++p) {
        int s = csr_src[p];
        float v = a2s[s] + ad; v = v > 0.f ? v : NEG * v;
        float w = __expf(v);
        acc = fmaf(w, __half2float(hw2h[(size_t)s * OUT_CH + o]), acc);
        wsum += w;
    }
    out[(size_t)d * OUT_CH + o] = acc / (wsum + 1e-16f) + b2[o];
}

extern "C" void kernel_launch(void* const* d_in, const int* in_sizes, int n_in,
                              void* d_out, int out_size, void* d_ws, size_t ws_size,
                              hipStream_t stream) {
    const float* x   = (const float*)d_in[0];
    const int*   ei  = (const int*)d_in[1];     // int32 (JAX x64 off)
    const float* W1  = (const float*)d_in[2];
    const float* as1 = (const float*)d_in[3];
    const float* ad1 = (const float*)d_in[4];
    const float* b1  = (const float*)d_in[5];
    const float* W2  = (const float*)d_in[6];
    const float* as2 = (const float*)d_in[7];
    const float* ad2 = (const float*)d_in[8];
    const float* b2  = (const float*)d_in[9];
    float* out = (float*)d_out;
    float* ws  = (float*)d_ws;

    // workspace layout (float offsets); peak 6,300,272 floats = 25.2 MB
    __half* xwh   = (__half*)ws;               // 6.4M halves (3.2M floats)
    __half* hw2h  = (__half*)(ws + 3200000);   // 1.6M halves (800K floats)
    float* a1s    = ws + 4000000;              // 200,000
    float* a1d    = ws + 4200000;              // 200,000
    float* a2s    = ws + 4400000;              //  50,000
    float* a2d    = ws + 4450000;              //  50,000
    int*   deg    = (int*)(ws + 4500000);      //  50,000
    int*   rowptr = (int*)(ws + 4550000);      //  50,016
    int*   parts  = (int*)(ws + 4600016);      //     256
    int*   csr_src= (int*)(ws + 4600272);      // 850,000
    int*   idx    = (int*)(ws + 5450272);      // 850,000 -> end 6,300,272

    hipMemsetAsync(deg, 0, (size_t)N_NODES * sizeof(int), stream);

    gemm1_fused<<<GEMM_BLOCKS + FILL_BLOCKS, 256, 0, stream>>>(
        x, W1, as1, ad1, ei, xwh, a1s, a1d, deg, idx);

    scan_s1  <<<NCHUNK, 256, 0, stream>>>(deg, rowptr, parts);
    scan_s2  <<<1, 256, 0, stream>>>(parts);
    scan_s3  <<<(N_NODES + 255) / 256, 256, 0, stream>>>(rowptr, parts);
    place_csr<<<(ETOT + 255) / 256, 256, 0, stream>>>(ei, idx, rowptr, csr_src);

    gather1_g2<<<N_NODES / 8, 256, 0, stream>>>(rowptr, csr_src, a1s, a1d, xwh,
                                                b1, W2, as2, ad2, hw2h, a2s, a2d);

    gather2  <<<(N_NODES + 7) / 8, 256, 0, stream>>>(rowptr, csr_src, a2s, a2d, hw2h, b2, out);
}

// Round 15
// 156.212 us; speedup vs baseline: 1.9914x; 1.0316x over previous
//
#include <hip/hip_runtime.h>
#include <hip/hip_fp16.h>

#define N_NODES 50000
#define E_EDGES 800000
#define ETOT (E_EDGES + N_NODES)   // self-loops appended
#define IN_CH 128
#define HH 128                     // HEADS*HID
#define HEADS 4
#define HID 32
#define OUT_CH 32
#define NEG 0.2f

#define GEMM_BLOCKS ((N_NODES + 127) / 128)   // 391
#define FILL_BLOCKS ((ETOT + 1023) / 1024)    // 831
#define XP 132                                // padded LDS row stride

// ===== fused: [blocks 0..390] xw1 = x@W1 + att dots ; [391..] edge-rank atomic pass =====
__global__ __launch_bounds__(256, 2) void gemm1_fused(const float* __restrict__ x,
                                                      const float* __restrict__ W1,
                                                      const float* __restrict__ att_s,
                                                      const float* __restrict__ att_d,
                                                      const int* __restrict__ ei,
                                                      __half* __restrict__ xwh,
                                                      float* __restrict__ a1s,
                                                      float* __restrict__ a1d,
                                                      int* __restrict__ deg,
                                                      int* __restrict__ idx) {
    __shared__ float Xs[32][XP];
    __shared__ float Ws[32][XP];
    int t = threadIdx.x;

    if (blockIdx.x >= GEMM_BLOCKS) {
        // ---------- edge-rank pass: idx[e] = rank of e within its dst group ----------
        int base = (blockIdx.x - GEMM_BLOCKS) * 1024 + t;
#pragma unroll
        for (int q = 0; q < 4; ++q) {
            int e = base + q * 256;
            if (e < ETOT) {
                int d = (e < E_EDGES) ? ei[E_EDGES + e] : e - E_EDGES;
                idx[e] = atomicAdd(deg + d, 1);
            }
        }
        return;
    }

    // ---------- GEMM part: 128x128 tile, BK=32, 8x8 micro-tile ----------
    int tx = t & 15, ty = t >> 4;
    int row0 = blockIdx.x * 128;
    float acc[8][8] = {};

    for (int k0 = 0; k0 < IN_CH; k0 += 32) {
#pragma unroll
        for (int p = 0; p < 4; ++p) {
            int i2 = t + p * 256;
            int kk = i2 >> 5, c4 = i2 & 31;
            float4 v = *(const float4*)&W1[(size_t)(k0 + kk) * HH + c4 * 4];
            *(float4*)&Ws[kk][c4 * 4] = v;
        }
#pragma unroll
        for (int p = 0; p < 4; ++p) {
            int i2 = t + p * 256;
            int rr = i2 >> 3, c4 = i2 & 7;
            int row = row0 + rr;
            float4 v = make_float4(0.f, 0.f, 0.f, 0.f);
            if (row < N_NODES) v = *(const float4*)&x[(size_t)row * IN_CH + k0 + c4 * 4];
            Xs[c4 * 4 + 0][rr] = v.x;
            Xs[c4 * 4 + 1][rr] = v.y;
            Xs[c4 * 4 + 2][rr] = v.z;
            Xs[c4 * 4 + 3][rr] = v.w;
        }
        __syncthreads();
#pragma unroll 8
        for (int kk = 0; kk < 32; ++kk) {
            float4 xa0 = *(const float4*)&Xs[kk][ty * 4];
            float4 xa1 = *(const float4*)&Xs[kk][ty * 4 + 64];
            float4 wb0 = *(const float4*)&Ws[kk][tx * 4];
            float4 wb1 = *(const float4*)&Ws[kk][tx * 4 + 64];
            float xa[8] = {xa0.x, xa0.y, xa0.z, xa0.w, xa1.x, xa1.y, xa1.z, xa1.w};
            float wb[8] = {wb0.x, wb0.y, wb0.z, wb0.w, wb1.x, wb1.y, wb1.z, wb1.w};
#pragma unroll
            for (int i = 0; i < 8; ++i)
#pragma unroll
                for (int j = 0; j < 8; ++j)
                    acc[i][j] = fmaf(xa[i], wb[j], acc[i][j]);
        }
        __syncthreads();
    }

    float asr[8], adr[8];
#pragma unroll
    for (int j = 0; j < 8; ++j) {
        int col = tx * 4 + (j & 3) + ((j >> 2) << 6);
        asr[j] = att_s[col];
        adr[j] = att_d[col];
    }
    int hA = tx >> 3;

#pragma unroll
    for (int i = 0; i < 8; ++i) {
        int row = row0 + ty * 4 + (i < 4 ? i : 60 + i);
        if (row < N_NODES) {
            union { __half2 h2; unsigned u; } c0, c1, c2, c3;
            c0.h2 = __floats2half2_rn(acc[i][0], acc[i][1]);
            c1.h2 = __floats2half2_rn(acc[i][2], acc[i][3]);
            c2.h2 = __floats2half2_rn(acc[i][4], acc[i][5]);
            c3.h2 = __floats2half2_rn(acc[i][6], acc[i][7]);
            *(uint2*)&xwh[(size_t)row * HH + tx * 4]      = make_uint2(c0.u, c1.u);
            *(uint2*)&xwh[(size_t)row * HH + tx * 4 + 64] = make_uint2(c2.u, c3.u);
        }
        float psA = 0.f, pdA = 0.f, psB = 0.f, pdB = 0.f;
#pragma unroll
        for (int j = 0; j < 4; ++j) {
            psA = fmaf(acc[i][j], asr[j], psA);
            pdA = fmaf(acc[i][j], adr[j], pdA);
            psB = fmaf(acc[i][j + 4], asr[j + 4], psB);
            pdB = fmaf(acc[i][j + 4], adr[j + 4], pdB);
        }
#pragma unroll
        for (int off = 1; off < 8; off <<= 1) {
            psA += __shfl_xor(psA, off, 16);
            pdA += __shfl_xor(pdA, off, 16);
            psB += __shfl_xor(psB, off, 16);
            pdB += __shfl_xor(pdB, off, 16);
        }
        if ((tx & 7) == 0 && row < N_NODES) {
            a1s[row * 4 + hA]     = psA;
            a1d[row * 4 + hA]     = pdA;
            a1s[row * 4 + hA + 2] = psB;
            a1d[row * 4 + hA + 2] = pdB;
        }
    }
}

// ================= scan (rowptr from deg) =================
__device__ __forceinline__ int block_incl_scan(int v, int t) {
    for (int off = 1; off < 64; off <<= 1) {
        int n = __shfl_up(v, off, 64);
        if ((t & 63) >= off) v += n;
    }
    __shared__ int wsum[4];
    if ((t & 63) == 63) wsum[t >> 6] = v;
    __syncthreads();
    int w = t >> 6;
    if (w > 0) {
        int add = 0;
        for (int k = 0; k < w; ++k) add += wsum[k];
        v += add;
    }
    __syncthreads();
    return v;
}

#define NCHUNK ((N_NODES + 255) / 256)   // 196

__global__ void scan_s1(const int* __restrict__ deg, int* __restrict__ rowptr,
                        int* __restrict__ partials) {
    int t = threadIdx.x;
    int i = blockIdx.x * 256 + t;
    int v = (i < N_NODES) ? deg[i] : 0;
    int s = block_incl_scan(v, t);
    if (i < N_NODES) rowptr[i + 1] = s;
    if (t == 255) partials[blockIdx.x] = s;
}

__global__ void scan_s2(int* __restrict__ partials) {
    int t = threadIdx.x;
    int v = (t < NCHUNK) ? partials[t] : 0;
    int s = block_incl_scan(v, t);
    if (t < NCHUNK) partials[t] = s;
}

__global__ void scan_s3(int* __restrict__ rowptr, const int* __restrict__ partials) {
    int i = blockIdx.x * blockDim.x + threadIdx.x;
    if (i == 0) rowptr[0] = 0;
    if (i < N_NODES) {
        int c = i >> 8;
        if (c > 0) rowptr[i + 1] += partials[c - 1];
    }
}

// ================= place: csr_src[rowptr[d]+idx[e]] = s (no atomics) =================
__global__ void place_csr(const int* __restrict__ ei, const int* __restrict__ idx,
                          const int* __restrict__ rowptr, int* __restrict__ csr_src) {
    int e = blockIdx.x * blockDim.x + threadIdx.x;
    if (e >= ETOT) return;
    int s, d;
    if (e < E_EDGES) { s = ei[e]; d = ei[E_EDGES + e]; }
    else { s = e - E_EDGES; d = s; }
    csr_src[rowptr[d] + idx[e]] = s;
}

// ========== layer-1 gather + fused denom + FUSED gemm2/att-dots ==========
// 2 nodes per 64-lane wave: 32 lanes/node, 4 channels/lane (8B gather per lane).
// Two independent edge streams per wave -> 2x outstanding gathers (latency lever).
// N_NODES % 8 == 0 -> every block has 8 full nodes (no early return vs barrier).
__global__ void gather1_g2(const int* __restrict__ rowptr, const int* __restrict__ csr_src,
                           const float* __restrict__ a1s, const float* __restrict__ a1d,
                           const __half* __restrict__ xwh,
                           const float* __restrict__ b1, const float* __restrict__ W2,
                           const float* __restrict__ att_s2, const float* __restrict__ att_d2,
                           __half* __restrict__ hw2h,
                           float* __restrict__ a2s, float* __restrict__ a2d) {
    __shared__ float Wl[HH * OUT_CH];   // W2 [j*32+o], 16 KiB; lane o -> bank o
    __shared__ float hs[8][HH];         // per-node h rows, 4 KiB
    int t = threadIdx.x;
    for (int i = t; i < HH * OUT_CH; i += 256) Wl[i] = W2[i];
    __syncthreads();

    int wid = t >> 5;                    // node slot 0..7
    int d = blockIdx.x * 8 + wid;
    int l = t & 31;                      // channels 4l..4l+3; head = l>>3
    int h = l >> 3;
    float ad = a1d[d * 4 + h];
    int p0 = rowptr[d], p1 = rowptr[d + 1];
    float acc0 = 0.f, acc1 = 0.f, acc2 = 0.f, acc3 = 0.f, wsum = 0.f;
    union { float2 f2; __half2 h2[2]; } u0, u1, u2, u3;
    int p = p0;
    for (; p + 3 < p1; p += 4) {
        int s0 = csr_src[p], s1 = csr_src[p + 1], s2 = csr_src[p + 2], s3 = csr_src[p + 3];
        float v0 = a1s[s0 * 4 + h] + ad; v0 = v0 > 0.f ? v0 : NEG * v0;
        float v1 = a1s[s1 * 4 + h] + ad; v1 = v1 > 0.f ? v1 : NEG * v1;
        float v2 = a1s[s2 * 4 + h] + ad; v2 = v2 > 0.f ? v2 : NEG * v2;
        float v3 = a1s[s3 * 4 + h] + ad; v3 = v3 > 0.f ? v3 : NEG * v3;
        float w0 = __expf(v0), w1 = __expf(v1), w2 = __expf(v2), w3 = __expf(v3);
        u0.f2 = *(const float2*)&xwh[(size_t)s0 * HH + 4 * l];
        u1.f2 = *(const float2*)&xwh[(size_t)s1 * HH + 4 * l];
        u2.f2 = *(const float2*)&xwh[(size_t)s2 * HH + 4 * l];
        u3.f2 = *(const float2*)&xwh[(size_t)s3 * HH + 4 * l];
#define FM(k, W) { float2 fa = __half22float2(u##k.h2[0]); float2 fb = __half22float2(u##k.h2[1]); \
                   acc0 = fmaf(W, fa.x, acc0); acc1 = fmaf(W, fa.y, acc1); \
                   acc2 = fmaf(W, fb.x, acc2); acc3 = fmaf(W, fb.y, acc3); }
        FM(0, w0) FM(1, w1) FM(2, w2) FM(3, w3)
#undef FM
        wsum += (w0 + w1) + (w2 + w3);
    }
    for (; p < p1; ++p) {
        int s = csr_src[p];
        float v = a1s[s * 4 + h] + ad; v = v > 0.f ? v : NEG * v;
        float w = __expf(v);
        u0.f2 = *(const float2*)&xwh[(size_t)s * HH + 4 * l];
        float2 fa = __half22float2(u0.h2[0]);
        float2 fb = __half22float2(u0.h2[1]);
        acc0 = fmaf(w, fa.x, acc0); acc1 = fmaf(w, fa.y, acc1);
        acc2 = fmaf(w, fb.x, acc2); acc3 = fmaf(w, fb.y, acc3);
        wsum += w;
    }
    float r = 1.f / (wsum + 1e-16f);
    float4 bv = *(const float4*)&b1[4 * l];
    float h0 = acc0 * r + bv.x;
    float h1 = acc1 * r + bv.y;
    float h2v = acc2 * r + bv.z;
    float h3v = acc3 * r + bv.w;
    h0  = h0  > 0.f ? h0  : (__expf(h0)  - 1.f);   // ELU
    h1  = h1  > 0.f ? h1  : (__expf(h1)  - 1.f);
    h2v = h2v > 0.f ? h2v : (__expf(h2v) - 1.f);
    h3v = h3v > 0.f ? h3v : (__expf(h3v) - 1.f);
    *(float4*)&hs[wid][4 * l] = make_float4(h0, h1, h2v, h3v);
    // same-wave LDS write->read: compiler enforces lgkmcnt ordering (wave-private rows)

    // ---- gemm2 part: out[o] = sum_j h[j]*W2[j][o]; lane o = l, full 128-dot ----
    const float* hrow = hs[wid];
    const float* wcol = &Wl[l];
    float acc = 0.f;
#pragma unroll 8
    for (int j = 0; j < 128; ++j) acc = fmaf(hrow[j], wcol[j * OUT_CH], acc);

    hw2h[(size_t)d * OUT_CH + l] = __float2half_rn(acc);

    float ps = acc * att_s2[l], pd = acc * att_d2[l];
#pragma unroll
    for (int off = 16; off; off >>= 1) {
        ps += __shfl_xor(ps, off, 32);
        pd += __shfl_xor(pd, off, 32);
    }
    if (l == 0) { a2s[d] = ps; a2d[d] = pd; }
}

// ========== layer-2 gather-aggregate, fused denominator, 4-edge ILP ==========
__global__ void gather2(const int* __restrict__ rowptr, const int* __restrict__ csr_src,
                        const float* __restrict__ a2s, const float* __restrict__ a2d,
                        const __half* __restrict__ hw2h, const float* __restrict__ b2,
                        float* __restrict__ out) {
    int t = threadIdx.x;
    int d = blockIdx.x * 8 + (t >> 5);   // 32 lanes per node
    if (d >= N_NODES) return;
    int o = t & 31;
    float ad = a2d[d];
    int p0 = rowptr[d], p1 = rowptr[d + 1];
    float acc = 0.f, wsum = 0.f;
    int p = p0;
    for (; p + 3 < p1; p += 4) {
        int s0 = csr_src[p], s1 = csr_src[p + 1], s2 = csr_src[p + 2], s3 = csr_src[p + 3];
        float v0 = a2s[s0] + ad; v0 = v0 > 0.f ? v0 : NEG * v0;
        float v1 = a2s[s1] + ad; v1 = v1 > 0.f ? v1 : NEG * v1;
        float v2 = a2s[s2] + ad; v2 = v2 > 0.f ? v2 : NEG * v2;
        float v3 = a2s[s3] + ad; v3 = v3 > 0.f ? v3 : NEG * v3;
        float w0 = __expf(v0), w1 = __expf(v1), w2 = __expf(v2), w3 = __expf(v3);
        float x0 = __half2float(hw2h[(size_t)s0 * OUT_CH + o]);
        float x1 = __half2float(hw2h[(size_t)s1 * OUT_CH + o]);
        float x2 = __half2float(hw2h[(size_t)s2 * OUT_CH + o]);
        float x3 = __half2float(hw2h[(size_t)s3 * OUT_CH + o]);
        acc = fmaf(w0, x0, acc); acc = fmaf(w1, x1, acc);
        acc = fmaf(w2, x2, acc); acc = fmaf(w3, x3, acc);
        wsum += (w0 + w1) + (w2 + w3);
    }
    for (; p < p1; ++p) {
        int s = csr_src[p];
        float v = a2s[s] + ad; v = v > 0.f ? v : NEG * v;
        float w = __expf(v);
        acc = fmaf(w, __half2float(hw2h[(size_t)s * OUT_CH + o]), acc);
        wsum += w;
    }
    out[(size_t)d * OUT_CH + o] = acc / (wsum + 1e-16f) + b2[o];
}

extern "C" void kernel_launch(void* const* d_in, const int* in_sizes, int n_in,
                              void* d_out, int out_size, void* d_ws, size_t ws_size,
                              hipStream_t stream) {
    const float* x   = (const float*)d_in[0];
    const int*   ei  = (const int*)d_in[1];     // int32 (JAX x64 off)
    const float* W1  = (const float*)d_in[2];
    const float* as1 = (const float*)d_in[3];
    const float* ad1 = (const float*)d_in[4];
    const float* b1  = (const float*)d_in[5];
    const float* W2  = (const float*)d_in[6];
    const float* as2 = (const float*)d_in[7];
    const float* ad2 = (const float*)d_in[8];
    const float* b2  = (const float*)d_in[9];
    float* out = (float*)d_out;
    float* ws  = (float*)d_ws;

    // workspace layout (float offsets); peak 6,300,272 floats = 25.2 MB
    __half* xwh   = (__half*)ws;               // 6.4M halves (3.2M floats)
    __half* hw2h  = (__half*)(ws + 3200000);   // 1.6M halves (800K floats)
    float* a1s    = ws + 4000000;              // 200,000
    float* a1d    = ws + 4200000;              // 200,000
    float* a2s    = ws + 4400000;              //  50,000
    float* a2d    = ws + 4450000;              //  50,000
    int*   deg    = (int*)(ws + 4500000);      //  50,000
    int*   rowptr = (int*)(ws + 4550000);      //  50,016
    int*   parts  = (int*)(ws + 4600016);      //     256
    int*   csr_src= (int*)(ws + 4600272);      // 850,000
    int*   idx    = (int*)(ws + 5450272);      // 850,000 -> end 6,300,272

    hipMemsetAsync(deg, 0, (size_t)N_NODES * sizeof(int), stream);

    gemm1_fused<<<GEMM_BLOCKS + FILL_BLOCKS, 256, 0, stream>>>(
        x, W1, as1, ad1, ei, xwh, a1s, a1d, deg, idx);

    scan_s1  <<<NCHUNK, 256, 0, stream>>>(deg, rowptr, parts);
    scan_s2  <<<1, 256, 0, stream>>>(parts);
    scan_s3  <<<(N_NODES + 255) / 256, 256, 0, stream>>>(rowptr, parts);
    place_csr<<<(ETOT + 255) / 256, 256, 0, stream>>>(ei, idx, rowptr, csr_src);

    gather1_g2<<<N_NODES / 8, 256, 0, stream>>>(rowptr, csr_src, a1s, a1d, xwh,
                                                b1, W2, as2, ad2, hw2h, a2s, a2d);

    gather2  <<<(N_NODES + 7) / 8, 256, 0, stream>>>(rowptr, csr_src, a2s, a2d, hw2h, b2, out);
}